// Round 13
// baseline (197.806 us; speedup 1.0000x reference)
//
#include <hip/hip_runtime.h>
#include <hip/hip_bf16.h>

using bf16x4 = __attribute__((ext_vector_type(4))) short;
using short8 = __attribute__((ext_vector_type(8))) short;
using f32x4  = __attribute__((ext_vector_type(4))) float;
using f32x16 = __attribute__((ext_vector_type(16))) float;
using u32x2  = __attribute__((ext_vector_type(2))) unsigned;

__device__ __forceinline__ short f2bf(float f) {
  unsigned u = __builtin_bit_cast(unsigned, f);
  u = (u + 0x7fffu + ((u >> 16) & 1u)) >> 16;  // RNE
  return (short)u;
}
__device__ __forceinline__ unsigned pk2(float a, float b) {
  __hip_bfloat162 h = __float22bfloat162_rn(make_float2(a, b));
  unsigned u; __builtin_memcpy(&u, &h, 4);
  return u;
}
__device__ __forceinline__ void gload16(const short* g, short* l) {
  __builtin_amdgcn_global_load_lds(
      (const __attribute__((address_space(1))) unsigned int*)g,
      (__attribute__((address_space(3))) unsigned int*)l, 16, 0, 0);
}
// exchange a.hi-lanes with b.lo-lanes (gfx950)
__device__ __forceinline__ void pl32swap(unsigned &a, unsigned &b) {
  asm("v_permlane32_swap_b32 %0, %1" : "+v"(a), "+v"(b));
}

constexpr int E  = 1024;
constexpr int SL = 2048;
constexpr int NB = 2;
constexpr int NH = 16;
constexpr int M  = NB * SL;  // 4096

// fp32 -> bf16 one-shot convert: out = Xb(4M) | Wq(1M) | Wk(1M) | Wv(1M) | Wo(1M)
__global__ __launch_bounds__(256) void convert_kernel(
    const float* __restrict__ X,  const float* __restrict__ Wq,
    const float* __restrict__ Wk, const float* __restrict__ Wv,
    const float* __restrict__ Wo, short* __restrict__ out)
{
  const size_t i8 = ((size_t)blockIdx.x * 256 + threadIdx.x) * 8;
  const float* src;
  if (i8 < (size_t)(4u << 20)) {
    src = X + i8;
  } else {
    size_t r = i8 - (size_t)(4u << 20);
    int wi = (int)(r >> 20);
    size_t off = r & ((1u << 20) - 1);
    src = (wi == 0 ? Wq : wi == 1 ? Wk : wi == 2 ? Wv : Wo) + off;
  }
  f32x4 a = *(const f32x4*)src;
  f32x4 b = *(const f32x4*)(src + 4);
  short hb[8];
#pragma unroll
  for (int e = 0; e < 4; ++e) { hb[e] = f2bf(a[e]); hb[4 + e] = f2bf(b[e]); }
  *(short8*)(out + i8) = *(short8*)hb;
}

// C[m,n] = sum_k A[m,k]*B[n,k]; 128x128 tile, BK=32, double-buffered LDS,
// one __syncthreads-pair barrier/iter (R4/R9-proven structure).
// PROJ (768 blocks, 3/CU): z0 Q^T (A=Wq), z1 K^T (A=Wk), z2 VT (A=X,B=Wv).
// OUT: SPLIT-K=2 (512 blocks, 2/CU). K-split keeps total staged bytes
//   EXACTLY constant (each half stages its half of the panels; union =
//   original) while doubling co-residency -- the mechanism that carries
//   proj (R2), without the staging-traffic growth that sank the TN-splits
//   (R3/R10). Half-0 writes `out` (+bias) via plain f32x4; half-1 writes
//   a 16 MB partial to dead ws (Kw region); combine_kernel adds them.
//   Deterministic -- no atomics, no new sync structure.
//   Per-XCD mapping: 4 token-panels x 8 feat-tiles x both k-halves
//   (same 3 MB L2 set as R12's n-major map).
// C^T-store epilogue: thread's 4 acc values = 4 consecutive m-rows of one
// n-col -> Y[col*ldY+row..+3] as u32x2 (bf16) / f32x4 (fp32).
template <bool OUTF32, bool PROJ>
__device__ __forceinline__ void gemm_body(
    const short* __restrict__ A0, const short* __restrict__ A1, const short* __restrict__ A2,
    const short* __restrict__ B0, const short* __restrict__ B1, const short* __restrict__ B2,
    const float* __restrict__ b0, const float* __restrict__ b1, const float* __restrict__ b2,
    void* __restrict__ Y0, void* __restrict__ Y1, void* __restrict__ Y2,
    float s0, float s1, float s2, int ld0, int ld1, int ld2)
{
  constexpr int BK = 32;
  constexpr int TM = 128, TN = 128;
  constexpr int RA = TM / 64;
  constexpr int RB = TN / 64;
  constexpr int WM = TM / 2, WN = TN / 2;
  constexpr int NI = WM / 16, NJ = WN / 16;
  __shared__ alignas(16) short As[2][TM * BK];
  __shared__ alignas(16) short Bs[2][TN * BK];
  const int t = threadIdx.x;
  const int l = t & 63;
  const int w = t >> 6;
  const int c = l & 15;
  const int g = l >> 4;

  // XCD-chunked swizzle: block fid -> XCD (fid&7); contiguous logical chunk.
  const int fid = (int)blockIdx.x;
  int z, m0, n0, kbeg = 0, kend = E;
  bool biasOn = true;
  void* Yovr = nullptr;
  if (PROJ) {
    const int orig = (fid & 7) * 96 + (fid >> 3);  // 768 blocks
    z = orig >> 8;                                  // 256 blocks per slice
    const int rem = orig & 255;                     // 8 m-tiles x 32 n-tiles
    const bool sw = (z != 2);
    m0 = (sw ? (rem >> 5) : (rem & 31)) * TM;
    n0 = (sw ? (rem & 31) : (rem >> 5)) * TN;
  } else {
    // 512 blocks: orig = xcd*64 + j. n-tile = orig>>4 (4 contiguous
    // token-panels per XCD), m-tile = (orig>>1)&7, k-half = orig&1.
    const int orig = (fid & 7) * 64 + (fid >> 3);
    z = 0;
    const int kh = orig & 1;
    m0 = ((orig >> 1) & 7) * TM;
    n0 = (orig >> 4) * TN;
    kbeg = kh * (E / 2);
    kend = kbeg + (E / 2);
    biasOn = (kh == 0);
    Yovr = kh ? Y1 : Y0;   // half-0 -> out, half-1 -> partial ws
  }
  const short* Ap = (z == 0) ? A0 : (z == 1) ? A1 : A2;
  const short* Bp = (z == 0) ? B0 : (z == 1) ? B1 : B2;
  const float* bp = (z == 0) ? b0 : (z == 1) ? b1 : b2;
  void* Yp        = PROJ ? ((z == 0) ? Y0 : (z == 1) ? Y1 : Y2) : Yovr;
  const float sc  = (z == 0) ? s0 : (z == 1) ? s1 : s2;
  const int ldY   = (z == 0) ? ld0 : (z == 1) ? ld1 : ld2;
  const bool swp  = PROJ ? (z != 2) : true;  // bias on m-side?

  const short* gA[RA]; int oA[RA];
  const short* gB[RB]; int oB[RB];
#pragma unroll
  for (int r = 0; r < RA; ++r) {
    const int cc = r * 256 + t;
    gA[r] = Ap + (size_t)(m0 + (cc >> 2)) * E + (cc & 3) * 8;
    oA[r] = (r * 256 + (t & ~63)) * 8;   // wave-uniform base (lane*16B by HW)
  }
#pragma unroll
  for (int r = 0; r < RB; ++r) {
    const int cc = r * 256 + t;
    gB[r] = Bp + (size_t)(n0 + (cc >> 2)) * E + (cc & 3) * 8;
    oB[r] = (r * 256 + (t & ~63)) * 8;
  }

  // prologue: first tile of this k-range -> buf 0
#pragma unroll
  for (int r = 0; r < RA; ++r) gload16(gA[r] + kbeg, &As[0][oA[r]]);
#pragma unroll
  for (int r = 0; r < RB; ++r) gload16(gB[r] + kbeg, &Bs[0][oB[r]]);

  const int wm = (w >> 1) * WM;
  const int wn = (w & 1) * WN;
  f32x4 acc[NI][NJ] = {};
  int cur = 0;

  for (int k0 = kbeg; k0 < kend; k0 += BK) {
    __syncthreads();
    if (k0 + BK < kend) {
#pragma unroll
      for (int r = 0; r < RA; ++r) gload16(gA[r] + k0 + BK, &As[cur ^ 1][oA[r]]);
#pragma unroll
      for (int r = 0; r < RB; ++r) gload16(gB[r] + k0 + BK, &Bs[cur ^ 1][oB[r]]);
    }
    short8 ah[NI], bfr[NJ];
#pragma unroll
    for (int i = 0; i < NI; ++i)
      ah[i] = *(const short8*)&As[cur][(wm + i * 16 + c) * BK + g * 8];
#pragma unroll
    for (int j = 0; j < NJ; ++j)
      bfr[j] = *(const short8*)&Bs[cur][(wn + j * 16 + c) * BK + g * 8];
#pragma unroll
    for (int i = 0; i < NI; ++i)
#pragma unroll
      for (int j = 0; j < NJ; ++j)
        acc[i][j] = __builtin_amdgcn_mfma_f32_16x16x32_bf16(ah[i], bfr[j], acc[i][j], 0, 0, 0);
    cur ^= 1;
  }

  // C/D: row(m) = g*4 + r, col(n) = c.  Store C^T: Y[col*ldY + row].
  float bm[NI][4];
  if (swp) {
#pragma unroll
    for (int i = 0; i < NI; ++i)
#pragma unroll
      for (int r = 0; r < 4; ++r)
        bm[i][r] = biasOn ? bp[m0 + wm + i * 16 + g * 4 + r] : 0.f;
  }
#pragma unroll
  for (int j = 0; j < NJ; ++j) {
    const int col = n0 + wn + j * 16 + c;
    const float bj = (swp || !biasOn) ? 0.f : bp[col];
#pragma unroll
    for (int i = 0; i < NI; ++i) {
      const int row = m0 + wm + i * 16 + g * 4;
      float v[4];
#pragma unroll
      for (int r = 0; r < 4; ++r)
        v[r] = (acc[i][j][r] + (swp ? bm[i][r] : bj)) * sc;
      if (OUTF32) {
        f32x4 o = {v[0], v[1], v[2], v[3]};
        *(f32x4*)((float*)Yp + (size_t)col * ldY + row) = o;
      } else {
        u32x2 o = {pk2(v[0], v[1]), pk2(v[2], v[3])};
        *(u32x2*)((short*)Yp + (size_t)col * ldY + row) = o;
      }
    }
  }
}

__global__ __launch_bounds__(256) void proj_kernel(
    const short* A0, const short* A1, const short* A2,
    const short* B0, const short* B1, const short* B2,
    const float* b0, const float* b1, const float* b2,
    void* Y0, void* Y1, void* Y2,
    float s0, float s1, float s2, int ld0, int ld1, int ld2)
{
  gemm_body<false, true>(A0, A1, A2, B0, B1, B2, b0, b1, b2,
                         Y0, Y1, Y2, s0, s1, s2, ld0, ld1, ld2);
}

__global__ __launch_bounds__(256) void out_kernel(
    const short* A0, const short* A1, const short* A2,
    const short* B0, const short* B1, const short* B2,
    const float* b0, const float* b1, const float* b2,
    void* Y0, void* Y1, void* Y2,
    float s0, float s1, float s2, int ld0, int ld1, int ld2)
{
  gemm_body<true, false>(A0, A1, A2, B0, B1, B2, b0, b1, b2,
                         Y0, Y1, Y2, s0, s1, s2, ld0, ld1, ld2);
}

// out += P1 (split-K combine), f32x4, one-shot. 4M f32 -> 4096 blocks.
__global__ __launch_bounds__(256) void combine_kernel(
    float* __restrict__ out, const float* __restrict__ p1)
{
  const size_t i4 = ((size_t)blockIdx.x * 256 + threadIdx.x) * 4;
  f32x4 a = *(const f32x4*)(out + i4);
  f32x4 b = *(const f32x4*)(p1 + i4);
#pragma unroll
  for (int e = 0; e < 4; ++e) a[e] += b[e];
  *(f32x4*)(out + i4) = a;
}

// Flash, S^T formulation on 32x32x16 MFMA. WIDE-Q geometry (R9-proven):
// 8 waves x 32 q = 256 q / block, 512 threads, grid 256 (1 block/CU,
// 8 waves/CU, ONE shared K/V staging copy per CU, reg-staged 2-DEEP
// prefetch across the barrier). T12 permlane softmax, swizzled 64x64
// K/V tiles, LDS double-buffer, setprio. Q pre-scaled by log2(e)/8 ->
// p = exp2(s~). XCD-chunked grid.
__global__ __launch_bounds__(512, 2) void flash_kernel(
    const short* __restrict__ Qm, const short* __restrict__ Km,
    const short* __restrict__ VTm, short* __restrict__ Oh)
{
  __shared__ alignas(16) short Ks[2][64][64];  // [key][d], swizzled
  __shared__ alignas(16) short Vt[2][64][64];  // [d][key], swizzled
  const int t = threadIdx.x;
  const int l = t & 63;
  const int w = t >> 6;      // wave 0..7 -> q-sub-block
  const int c = l & 31;      // A-row / B-col lane index
  const int hi = l >> 5;     // k-half
  const int fid = (int)blockIdx.x;
  const int orig = (fid & 7) * 32 + (fid >> 3);  // 256 blocks, chunk 32
  const int q0 = (orig & 7) * 256;
  const int bh = orig >> 3;
  const int bat = bh >> 4;
  const int h = bh & 15;
  const size_t baseK = (size_t)bat * SL * E + h * 64;            // Q/K [token][feat]
  const size_t baseV = (size_t)(h * 64) * M + (size_t)bat * SL;  // V^T [feat][token]

  // Q B-fragments: col=q=c, k = tt*16 + hi*8 + e
  short8 qf[4];
  {
    const short* qp = Qm + baseK + (size_t)(q0 + w * 32 + c) * E + hi * 8;
#pragma unroll
    for (int tt = 0; tt < 4; ++tt) qf[tt] = *(const short8*)(qp + tt * 16);
  }

  // staging map: 512 chunks/matrix over 512 thr -> 1 K + 1 V chunk each.
  // thread t -> row t>>3 (0..63), 16B seg t&7; swizzle col by row&7.
  const int sr = t >> 3, sg = t & 7;
  const int swz = (sg ^ (sr & 7)) * 8;
  const short* gK0 = Km + baseK + (size_t)sr * E + sg * 8;
  const short* gV0 = VTm + baseV + (size_t)sr * M + sg * 8;
  const int wo0 = sr * 64 + swz;

  short8 k0r, v0r;
  // issue tile 0
  k0r = *(const short8*)gK0;
  v0r = *(const short8*)gV0;
  // commit tile 0 -> buf 0
  *(short8*)(&Ks[0][0][0] + wo0) = k0r;
  *(short8*)(&Vt[0][0][0] + wo0) = v0r;
  // issue tile 1
  k0r = *(const short8*)(gK0 + (size_t)64 * E);
  v0r = *(const short8*)(gV0 + 64);

  f32x16 oa0 = {}, oa1 = {};           // O^T accum, d-blocks 0/1
  f32x4 lacc = {0.f, 0.f, 0.f, 0.f};   // softmax denom partials
  __syncthreads();

  constexpr int NTT = SL / 64;         // 32 tiles
  const int sx = c & 7;
  for (int kt = 0; kt < NTT; ++kt) {
    const int cur = kt & 1;
    if (kt + 1 < NTT) {
      *(short8*)(&Ks[cur ^ 1][0][0] + wo0) = k0r;
      *(short8*)(&Vt[cur ^ 1][0][0] + wo0) = v0r;
      if (kt + 2 < NTT) {
        k0r = *(const short8*)(gK0 + (size_t)(kt + 2) * 64 * E);
        v0r = *(const short8*)(gV0 + (kt + 2) * 64);
      }
    }
    const short* Kc0 = &Ks[cur][c][0];
    const short* Kc1 = &Ks[cur][32 + c][0];
    const short* Vc0 = &Vt[cur][c][0];
    const short* Vc1 = &Vt[cur][32 + c][0];

    // S^T[key][q] = sum_d K[key][d] Q[q][d]; key-blocks 0/1
    f32x16 st0 = {}, st1 = {};
    __builtin_amdgcn_s_setprio(1);
#pragma unroll
    for (int tt = 0; tt < 4; ++tt) {
      const int off = ((tt * 2 + hi) ^ sx) * 8;
      short8 kf0 = *(const short8*)(Kc0 + off);
      short8 kf1 = *(const short8*)(Kc1 + off);
      st0 = __builtin_amdgcn_mfma_f32_32x32x16_bf16(kf0, qf[tt], st0, 0, 0, 0);
      st1 = __builtin_amdgcn_mfma_f32_32x32x16_bf16(kf1, qf[tt], st1, 0, 0, 0);
    }
    __builtin_amdgcn_s_setprio(0);

    // p = 2^st, denom partials; reg i -> key (i&3) + 8*(i>>2) + 4*hi
    float p0[16], p1[16];
#pragma unroll
    for (int i = 0; i < 16; ++i) p0[i] = __builtin_amdgcn_exp2f(st0[i]);
#pragma unroll
    for (int i = 0; i < 16; ++i) p1[i] = __builtin_amdgcn_exp2f(st1[i]);
#pragma unroll
    for (int i = 0; i < 16; ++i) lacc[i & 3] += p0[i] + p1[i];

    // pack own-hi key pairs: W[b][0]=keys(8b+4hi+0,1) W[b][1]=keys(8b+4hi+2,3)
    unsigned W0[4][2], W1[4][2];
#pragma unroll
    for (int b8 = 0; b8 < 4; ++b8) {
      W0[b8][0] = pk2(p0[4 * b8 + 0], p0[4 * b8 + 1]);
      W0[b8][1] = pk2(p0[4 * b8 + 2], p0[4 * b8 + 3]);
      W1[b8][0] = pk2(p1[4 * b8 + 0], p1[4 * b8 + 1]);
      W1[b8][1] = pk2(p1[4 * b8 + 2], p1[4 * b8 + 3]);
    }

    // O^T[d][q] += V^T[d][k] P[k][q]; P B-frag per k-step via 2 permlane swaps
    __builtin_amdgcn_s_setprio(1);
#pragma unroll
    for (int tt = 0; tt < 4; ++tt) {
      unsigned a0, a1, b0, b1;
      if (tt == 0)      { a0 = W0[0][0]; a1 = W0[0][1]; b0 = W0[1][0]; b1 = W0[1][1]; }
      else if (tt == 1) { a0 = W0[2][0]; a1 = W0[2][1]; b0 = W0[3][0]; b1 = W0[3][1]; }
      else if (tt == 2) { a0 = W1[0][0]; a1 = W1[0][1]; b0 = W1[1][0]; b1 = W1[1][1]; }
      else              { a0 = W1[2][0]; a1 = W1[2][1]; b0 = W1[3][0]; b1 = W1[3][1]; }
      pl32swap(a0, b0);   // -> frag u32[0] (e0,1) and u32[2] (e4,5)
      pl32swap(a1, b1);   // -> frag u32[1] (e2,3) and u32[3] (e6,7)
      union { unsigned u[4]; short8 s8; } pf;
      pf.u[0] = a0; pf.u[1] = a1; pf.u[2] = b0; pf.u[3] = b1;
      const int off = ((tt * 2 + hi) ^ sx) * 8;
      short8 vf0 = *(const short8*)(Vc0 + off);
      short8 vf1 = *(const short8*)(Vc1 + off);
      oa0 = __builtin_amdgcn_mfma_f32_32x32x16_bf16(vf0, pf.s8, oa0, 0, 0, 0);
      oa1 = __builtin_amdgcn_mfma_f32_32x32x16_bf16(vf1, pf.s8, oa1, 0, 0, 0);
    }
    __builtin_amdgcn_s_setprio(0);
    __syncthreads();
  }

  float s = lacc[0] + lacc[1] + lacc[2] + lacc[3];
  s += __shfl_xor(s, 32);
  const float inv = 1.0f / s;
  const int q = q0 + w * 32 + c;
  short* op = Oh + ((size_t)bat * SL + q) * E + h * 64 + hi * 4;
#pragma unroll
  for (int b8 = 0; b8 < 4; ++b8) {
    u32x2 t0 = {pk2(oa0[4 * b8 + 0] * inv, oa0[4 * b8 + 1] * inv),
                pk2(oa0[4 * b8 + 2] * inv, oa0[4 * b8 + 3] * inv)};
    *(u32x2*)(op + b8 * 8) = t0;
    u32x2 t1 = {pk2(oa1[4 * b8 + 0] * inv, oa1[4 * b8 + 1] * inv),
                pk2(oa1[4 * b8 + 2] * inv, oa1[4 * b8 + 3] * inv)};
    *(u32x2*)(op + 32 + b8 * 8) = t1;
  }
}

extern "C" void kernel_launch(void* const* d_in, const int* in_sizes, int n_in,
                              void* d_out, int out_size, void* d_ws, size_t ws_size,
                              hipStream_t stream)
{
  const float* X  = (const float*)d_in[0];
  const float* Wq = (const float*)d_in[1];
  const float* bq = (const float*)d_in[2];
  const float* Wk = (const float*)d_in[3];
  const float* bk = (const float*)d_in[4];
  const float* Wv = (const float*)d_in[5];
  const float* bv = (const float*)d_in[6];
  const float* Wo = (const float*)d_in[7];
  const float* bo = (const float*)d_in[8];
  float* out = (float*)d_out;

  const size_t szX = (size_t)M * E;       // 4M elems
  const size_t szW = (size_t)E * E;       // 1M elems
  short* Xb  = (short*)d_ws;
  short* Wqb = Xb + szX;
  short* Wkb = Wqb + szW;
  short* Wvb = Wkb + szW;
  short* Wob = Wvb + szW;
  short* Qw  = Wob + szW;                 // later reused as Oh
  short* Kw  = Qw + szX;
  short* VTw = Kw + szX;                  // [1024][4096]; total ws 40 MB
  float* P1  = (float*)Kw;                // split-K partial: Kw+VTw region
                                          // (16 MB, dead after flash)

  convert_kernel<<<4096, 256, 0, stream>>>(X, Wq, Wk, Wv, Wo, Xb);

  // Fused projections (C^T-store, 128x128, BK=32, XCD-chunked; R4 form):
  // z0 Q (A=Wq, scaled log2e/8), z1 K (A=Wk), z2 V^T (A=X, B=Wv).
  const float kLog2eOver8 = 0.18033688011112042f;
  proj_kernel<<<768, 256, 0, stream>>>(
      Wqb, Wkb, Xb,
      Xb, Xb, Wvb,
      bq, bk, bv,
      (void*)Qw, (void*)Kw, (void*)VTw,
      kLog2eOver8, 1.0f, 1.0f, E, E, M);

  // 256 blocks x 512 threads (8 waves, q-tile 256): 1 block/CU, one
  // shared K/V staging copy per CU, reg-staged 2-deep prefetch (R9 form).
  flash_kernel<<<256, 512, 0, stream>>>(Qw, Kw, VTw, Qw /*Oh in-place*/);

  // Final: out[token][feat] = Oh@Wo^T + bo; A=Wo (m=feat), B=Oh (n=token).
  // SPLIT-K=2: 512 blocks = 2/CU, half-0 -> out (+bias), half-1 -> P1;
  // then out += P1 (deterministic combine, no atomics).
  out_kernel<<<512, 256, 0, stream>>>(
      Wob, Wob, Wob,
      Qw, Qw, Qw,
      bo, bo, bo,
      (void*)out, (void*)P1, (void*)out,
      1.0f, 1.0f, 1.0f, E, E, E);

  combine_kernel<<<4096, 256, 0, stream>>>(out, P1);
}

// Round 14
// 190.350 us; speedup vs baseline: 1.0392x; 1.0392x over previous
//
#include <hip/hip_runtime.h>
#include <hip/hip_bf16.h>

using bf16x4 = __attribute__((ext_vector_type(4))) short;
using short8 = __attribute__((ext_vector_type(8))) short;
using f32x4  = __attribute__((ext_vector_type(4))) float;
using f32x16 = __attribute__((ext_vector_type(16))) float;
using u32x2  = __attribute__((ext_vector_type(2))) unsigned;

__device__ __forceinline__ short f2bf(float f) {
  unsigned u = __builtin_bit_cast(unsigned, f);
  u = (u + 0x7fffu + ((u >> 16) & 1u)) >> 16;  // RNE
  return (short)u;
}
__device__ __forceinline__ unsigned pk2(float a, float b) {
  __hip_bfloat162 h = __float22bfloat162_rn(make_float2(a, b));
  unsigned u; __builtin_memcpy(&u, &h, 4);
  return u;
}
__device__ __forceinline__ void gload16(const short* g, short* l) {
  __builtin_amdgcn_global_load_lds(
      (const __attribute__((address_space(1))) unsigned int*)g,
      (__attribute__((address_space(3))) unsigned int*)l, 16, 0, 0);
}
// exchange a.hi-lanes with b.lo-lanes (gfx950)
__device__ __forceinline__ void pl32swap(unsigned &a, unsigned &b) {
  asm("v_permlane32_swap_b32 %0, %1" : "+v"(a), "+v"(b));
}

constexpr int E  = 1024;
constexpr int SL = 2048;
constexpr int NB = 2;
constexpr int NH = 16;
constexpr int M  = NB * SL;  // 4096

// fp32 -> bf16 one-shot convert: out = Xb(4M) | Wq(1M) | Wk(1M) | Wv(1M) | Wo(1M)
__global__ __launch_bounds__(256) void convert_kernel(
    const float* __restrict__ X,  const float* __restrict__ Wq,
    const float* __restrict__ Wk, const float* __restrict__ Wv,
    const float* __restrict__ Wo, short* __restrict__ out)
{
  const size_t i8 = ((size_t)blockIdx.x * 256 + threadIdx.x) * 8;
  const float* src;
  if (i8 < (size_t)(4u << 20)) {
    src = X + i8;
  } else {
    size_t r = i8 - (size_t)(4u << 20);
    int wi = (int)(r >> 20);
    size_t off = r & ((1u << 20) - 1);
    src = (wi == 0 ? Wq : wi == 1 ? Wk : wi == 2 ? Wv : Wo) + off;
  }
  f32x4 a = *(const f32x4*)src;
  f32x4 b = *(const f32x4*)(src + 4);
  short hb[8];
#pragma unroll
  for (int e = 0; e < 4; ++e) { hb[e] = f2bf(a[e]); hb[4 + e] = f2bf(b[e]); }
  *(short8*)(out + i8) = *(short8*)hb;
}

// C[m,n] = sum_k A[m,k]*B[n,k]; 128x128 tile, BK=32, double-buffered LDS,
// one __syncthreads-pair barrier/iter (R4/R9-proven structure).
// XCD-chunked bijective block swizzle (T1) with WEIGHT-AXIS-INNER tile
// order everywhere: the 2 MB weight matrix is the innermost (8-tile) loop
// so it stays L2-resident per XCD while the X/token axis streams one
// 0.25 MB panel at a time (working set ~2.25 MB < 4 MB L2). Previous
// proj order streamed all 8 MB of Xb through every XCD's L2
// (FETCH 32.6 MB vs ~14 MB unique).
// PROJ (768 blocks, 3/CU): z0 Q^T (A=Wq), z1 K^T (A=Wk), z2 VT (A=X,B=Wv).
// OUT (256 blocks, 1/CU, R12 form): A=Wo (m=feat), B=Oh (n=token).
// C^T-store epilogue: thread's 4 acc values = 4 consecutive m-rows of one
// n-col -> Y[col*ldY+row..+3] as u32x2 (bf16) / f32x4 (fp32).
template <bool OUTF32, bool PROJ>
__device__ __forceinline__ void gemm_body(
    const short* __restrict__ A0, const short* __restrict__ A1, const short* __restrict__ A2,
    const short* __restrict__ B0, const short* __restrict__ B1, const short* __restrict__ B2,
    const float* __restrict__ b0, const float* __restrict__ b1, const float* __restrict__ b2,
    void* __restrict__ Y0, void* __restrict__ Y1, void* __restrict__ Y2,
    float s0, float s1, float s2, int ld0, int ld1, int ld2)
{
  constexpr int BK = 32;
  constexpr int TM = 128, TN = 128;
  constexpr int RA = TM / 64;
  constexpr int RB = TN / 64;
  constexpr int WM = TM / 2, WN = TN / 2;
  constexpr int NI = WM / 16, NJ = WN / 16;
  __shared__ alignas(16) short As[2][TM * BK];
  __shared__ alignas(16) short Bs[2][TN * BK];
  const int t = threadIdx.x;
  const int l = t & 63;
  const int w = t >> 6;
  const int c = l & 15;
  const int g = l >> 4;

  // XCD-chunked swizzle: block fid -> XCD (fid&7); contiguous logical chunk.
  const int fid = (int)blockIdx.x;
  int z, m0, n0;
  if (PROJ) {
    const int orig = (fid & 7) * 96 + (fid >> 3);  // 768 blocks
    z = orig >> 8;                                  // 256 blocks per slice
    const int rem = orig & 255;
    const bool sw = (z != 2);
    if (sw) {  // z0/z1: weight = A (8 m-tiles) -> m INNER, n outer streams
      m0 = (rem & 7) * TM;
      n0 = (rem >> 3) * TN;
    } else {   // z2: weight = B (8 n-tiles) -> n INNER, m outer streams
      m0 = (rem >> 3) * TM;
      n0 = (rem & 7) * TN;
    }
  } else {
    const int orig = (fid & 7) * 32 + (fid >> 3);  // 256 blocks
    z = 0;
    m0 = (orig & 7) * TM;                           // weight (feat) INNER
    n0 = (orig >> 3) * TN;                          // token outer streams
  }
  const short* Ap = (z == 0) ? A0 : (z == 1) ? A1 : A2;
  const short* Bp = (z == 0) ? B0 : (z == 1) ? B1 : B2;
  const float* bp = (z == 0) ? b0 : (z == 1) ? b1 : b2;
  void* Yp        = (z == 0) ? Y0 : (z == 1) ? Y1 : Y2;
  const float sc  = (z == 0) ? s0 : (z == 1) ? s1 : s2;
  const int ldY   = (z == 0) ? ld0 : (z == 1) ? ld1 : ld2;
  const bool swp  = PROJ ? (z != 2) : true;  // bias on m-side?

  const short* gA[RA]; int oA[RA];
  const short* gB[RB]; int oB[RB];
#pragma unroll
  for (int r = 0; r < RA; ++r) {
    const int cc = r * 256 + t;
    gA[r] = Ap + (size_t)(m0 + (cc >> 2)) * E + (cc & 3) * 8;
    oA[r] = (r * 256 + (t & ~63)) * 8;   // wave-uniform base (lane*16B by HW)
  }
#pragma unroll
  for (int r = 0; r < RB; ++r) {
    const int cc = r * 256 + t;
    gB[r] = Bp + (size_t)(n0 + (cc >> 2)) * E + (cc & 3) * 8;
    oB[r] = (r * 256 + (t & ~63)) * 8;
  }

  // prologue: tile 0 -> buf 0
#pragma unroll
  for (int r = 0; r < RA; ++r) gload16(gA[r], &As[0][oA[r]]);
#pragma unroll
  for (int r = 0; r < RB; ++r) gload16(gB[r], &Bs[0][oB[r]]);

  const int wm = (w >> 1) * WM;
  const int wn = (w & 1) * WN;
  f32x4 acc[NI][NJ] = {};
  int cur = 0;

  for (int k0 = 0; k0 < E; k0 += BK) {
    __syncthreads();
    if (k0 + BK < E) {
#pragma unroll
      for (int r = 0; r < RA; ++r) gload16(gA[r] + k0 + BK, &As[cur ^ 1][oA[r]]);
#pragma unroll
      for (int r = 0; r < RB; ++r) gload16(gB[r] + k0 + BK, &Bs[cur ^ 1][oB[r]]);
    }
    short8 ah[NI], bfr[NJ];
#pragma unroll
    for (int i = 0; i < NI; ++i)
      ah[i] = *(const short8*)&As[cur][(wm + i * 16 + c) * BK + g * 8];
#pragma unroll
    for (int j = 0; j < NJ; ++j)
      bfr[j] = *(const short8*)&Bs[cur][(wn + j * 16 + c) * BK + g * 8];
#pragma unroll
    for (int i = 0; i < NI; ++i)
#pragma unroll
      for (int j = 0; j < NJ; ++j)
        acc[i][j] = __builtin_amdgcn_mfma_f32_16x16x32_bf16(ah[i], bfr[j], acc[i][j], 0, 0, 0);
    cur ^= 1;
  }

  // C/D: row(m) = g*4 + r, col(n) = c.  Store C^T: Y[col*ldY + row].
  float bm[NI][4];
  if (swp) {
#pragma unroll
    for (int i = 0; i < NI; ++i)
#pragma unroll
      for (int r = 0; r < 4; ++r)
        bm[i][r] = bp[m0 + wm + i * 16 + g * 4 + r];
  }
#pragma unroll
  for (int j = 0; j < NJ; ++j) {
    const int col = n0 + wn + j * 16 + c;
    const float bj = swp ? 0.f : bp[col];
#pragma unroll
    for (int i = 0; i < NI; ++i) {
      const int row = m0 + wm + i * 16 + g * 4;
      float v[4];
#pragma unroll
      for (int r = 0; r < 4; ++r)
        v[r] = (acc[i][j][r] + (swp ? bm[i][r] : bj)) * sc;
      if (OUTF32) {
        f32x4 o = {v[0], v[1], v[2], v[3]};
        *(f32x4*)((float*)Yp + (size_t)col * ldY + row) = o;
      } else {
        u32x2 o = {pk2(v[0], v[1]), pk2(v[2], v[3])};
        *(u32x2*)((short*)Yp + (size_t)col * ldY + row) = o;
      }
    }
  }
}

__global__ __launch_bounds__(256) void proj_kernel(
    const short* A0, const short* A1, const short* A2,
    const short* B0, const short* B1, const short* B2,
    const float* b0, const float* b1, const float* b2,
    void* Y0, void* Y1, void* Y2,
    float s0, float s1, float s2, int ld0, int ld1, int ld2)
{
  gemm_body<false, true>(A0, A1, A2, B0, B1, B2, b0, b1, b2,
                         Y0, Y1, Y2, s0, s1, s2, ld0, ld1, ld2);
}

__global__ __launch_bounds__(256) void out_kernel(
    const short* A0, const short* A1, const short* A2,
    const short* B0, const short* B1, const short* B2,
    const float* b0, const float* b1, const float* b2,
    void* Y0, void* Y1, void* Y2,
    float s0, float s1, float s2, int ld0, int ld1, int ld2)
{
  gemm_body<true, false>(A0, A1, A2, B0, B1, B2, b0, b1, b2,
                         Y0, Y1, Y2, s0, s1, s2, ld0, ld1, ld2);
}

// Flash, S^T formulation on 32x32x16 MFMA. WIDE-Q geometry (R9-proven):
// 8 waves x 32 q = 256 q / block, 512 threads, grid 256 (1 block/CU,
// 8 waves/CU, ONE shared K/V staging copy per CU, reg-staged 2-DEEP
// prefetch across the barrier). T12 permlane softmax, swizzled 64x64
// K/V tiles, LDS double-buffer, setprio. Q pre-scaled by log2(e)/8 ->
// p = exp2(s~). XCD-chunked grid.
__global__ __launch_bounds__(512, 2) void flash_kernel(
    const short* __restrict__ Qm, const short* __restrict__ Km,
    const short* __restrict__ VTm, short* __restrict__ Oh)
{
  __shared__ alignas(16) short Ks[2][64][64];  // [key][d], swizzled
  __shared__ alignas(16) short Vt[2][64][64];  // [d][key], swizzled
  const int t = threadIdx.x;
  const int l = t & 63;
  const int w = t >> 6;      // wave 0..7 -> q-sub-block
  const int c = l & 31;      // A-row / B-col lane index
  const int hi = l >> 5;     // k-half
  const int fid = (int)blockIdx.x;
  const int orig = (fid & 7) * 32 + (fid >> 3);  // 256 blocks, chunk 32
  const int q0 = (orig & 7) * 256;
  const int bh = orig >> 3;
  const int bat = bh >> 4;
  const int h = bh & 15;
  const size_t baseK = (size_t)bat * SL * E + h * 64;            // Q/K [token][feat]
  const size_t baseV = (size_t)(h * 64) * M + (size_t)bat * SL;  // V^T [feat][token]

  // Q B-fragments: col=q=c, k = tt*16 + hi*8 + e
  short8 qf[4];
  {
    const short* qp = Qm + baseK + (size_t)(q0 + w * 32 + c) * E + hi * 8;
#pragma unroll
    for (int tt = 0; tt < 4; ++tt) qf[tt] = *(const short8*)(qp + tt * 16);
  }

  // staging map: 512 chunks/matrix over 512 thr -> 1 K + 1 V chunk each.
  // thread t -> row t>>3 (0..63), 16B seg t&7; swizzle col by row&7.
  const int sr = t >> 3, sg = t & 7;
  const int swz = (sg ^ (sr & 7)) * 8;
  const short* gK0 = Km + baseK + (size_t)sr * E + sg * 8;
  const short* gV0 = VTm + baseV + (size_t)sr * M + sg * 8;
  const int wo0 = sr * 64 + swz;

  short8 k0r, v0r;
  // issue tile 0
  k0r = *(const short8*)gK0;
  v0r = *(const short8*)gV0;
  // commit tile 0 -> buf 0
  *(short8*)(&Ks[0][0][0] + wo0) = k0r;
  *(short8*)(&Vt[0][0][0] + wo0) = v0r;
  // issue tile 1
  k0r = *(const short8*)(gK0 + (size_t)64 * E);
  v0r = *(const short8*)(gV0 + 64);

  f32x16 oa0 = {}, oa1 = {};           // O^T accum, d-blocks 0/1
  f32x4 lacc = {0.f, 0.f, 0.f, 0.f};   // softmax denom partials
  __syncthreads();

  constexpr int NTT = SL / 64;         // 32 tiles
  const int sx = c & 7;
  for (int kt = 0; kt < NTT; ++kt) {
    const int cur = kt & 1;
    if (kt + 1 < NTT) {
      *(short8*)(&Ks[cur ^ 1][0][0] + wo0) = k0r;
      *(short8*)(&Vt[cur ^ 1][0][0] + wo0) = v0r;
      if (kt + 2 < NTT) {
        k0r = *(const short8*)(gK0 + (size_t)(kt + 2) * 64 * E);
        v0r = *(const short8*)(gV0 + (kt + 2) * 64);
      }
    }
    const short* Kc0 = &Ks[cur][c][0];
    const short* Kc1 = &Ks[cur][32 + c][0];
    const short* Vc0 = &Vt[cur][c][0];
    const short* Vc1 = &Vt[cur][32 + c][0];

    // S^T[key][q] = sum_d K[key][d] Q[q][d]; key-blocks 0/1
    f32x16 st0 = {}, st1 = {};
    __builtin_amdgcn_s_setprio(1);
#pragma unroll
    for (int tt = 0; tt < 4; ++tt) {
      const int off = ((tt * 2 + hi) ^ sx) * 8;
      short8 kf0 = *(const short8*)(Kc0 + off);
      short8 kf1 = *(const short8*)(Kc1 + off);
      st0 = __builtin_amdgcn_mfma_f32_32x32x16_bf16(kf0, qf[tt], st0, 0, 0, 0);
      st1 = __builtin_amdgcn_mfma_f32_32x32x16_bf16(kf1, qf[tt], st1, 0, 0, 0);
    }
    __builtin_amdgcn_s_setprio(0);

    // p = 2^st, denom partials; reg i -> key (i&3) + 8*(i>>2) + 4*hi
    float p0[16], p1[16];
#pragma unroll
    for (int i = 0; i < 16; ++i) p0[i] = __builtin_amdgcn_exp2f(st0[i]);
#pragma unroll
    for (int i = 0; i < 16; ++i) p1[i] = __builtin_amdgcn_exp2f(st1[i]);
#pragma unroll
    for (int i = 0; i < 16; ++i) lacc[i & 3] += p0[i] + p1[i];

    // pack own-hi key pairs: W[b][0]=keys(8b+4hi+0,1) W[b][1]=keys(8b+4hi+2,3)
    unsigned W0[4][2], W1[4][2];
#pragma unroll
    for (int b8 = 0; b8 < 4; ++b8) {
      W0[b8][0] = pk2(p0[4 * b8 + 0], p0[4 * b8 + 1]);
      W0[b8][1] = pk2(p0[4 * b8 + 2], p0[4 * b8 + 3]);
      W1[b8][0] = pk2(p1[4 * b8 + 0], p1[4 * b8 + 1]);
      W1[b8][1] = pk2(p1[4 * b8 + 2], p1[4 * b8 + 3]);
    }

    // O^T[d][q] += V^T[d][k] P[k][q]; P B-frag per k-step via 2 permlane swaps
    __builtin_amdgcn_s_setprio(1);
#pragma unroll
    for (int tt = 0; tt < 4; ++tt) {
      unsigned a0, a1, b0, b1;
      if (tt == 0)      { a0 = W0[0][0]; a1 = W0[0][1]; b0 = W0[1][0]; b1 = W0[1][1]; }
      else if (tt == 1) { a0 = W0[2][0]; a1 = W0[2][1]; b0 = W0[3][0]; b1 = W0[3][1]; }
      else if (tt == 2) { a0 = W1[0][0]; a1 = W1[0][1]; b0 = W1[1][0]; b1 = W1[1][1]; }
      else              { a0 = W1[2][0]; a1 = W1[2][1]; b0 = W1[3][0]; b1 = W1[3][1]; }
      pl32swap(a0, b0);   // -> frag u32[0] (e0,1) and u32[2] (e4,5)
      pl32swap(a1, b1);   // -> frag u32[1] (e2,3) and u32[3] (e6,7)
      union { unsigned u[4]; short8 s8; } pf;
      pf.u[0] = a0; pf.u[1] = a1; pf.u[2] = b0; pf.u[3] = b1;
      const int off = ((tt * 2 + hi) ^ sx) * 8;
      short8 vf0 = *(const short8*)(Vc0 + off);
      short8 vf1 = *(const short8*)(Vc1 + off);
      oa0 = __builtin_amdgcn_mfma_f32_32x32x16_bf16(vf0, pf.s8, oa0, 0, 0, 0);
      oa1 = __builtin_amdgcn_mfma_f32_32x32x16_bf16(vf1, pf.s8, oa1, 0, 0, 0);
    }
    __builtin_amdgcn_s_setprio(0);
    __syncthreads();
  }

  float s = lacc[0] + lacc[1] + lacc[2] + lacc[3];
  s += __shfl_xor(s, 32);
  const float inv = 1.0f / s;
  const int q = q0 + w * 32 + c;
  short* op = Oh + ((size_t)bat * SL + q) * E + h * 64 + hi * 4;
#pragma unroll
  for (int b8 = 0; b8 < 4; ++b8) {
    u32x2 t0 = {pk2(oa0[4 * b8 + 0] * inv, oa0[4 * b8 + 1] * inv),
                pk2(oa0[4 * b8 + 2] * inv, oa0[4 * b8 + 3] * inv)};
    *(u32x2*)(op + b8 * 8) = t0;
    u32x2 t1 = {pk2(oa1[4 * b8 + 0] * inv, oa1[4 * b8 + 1] * inv),
                pk2(oa1[4 * b8 + 2] * inv, oa1[4 * b8 + 3] * inv)};
    *(u32x2*)(op + 32 + b8 * 8) = t1;
  }
}

extern "C" void kernel_launch(void* const* d_in, const int* in_sizes, int n_in,
                              void* d_out, int out_size, void* d_ws, size_t ws_size,
                              hipStream_t stream)
{
  const float* X  = (const float*)d_in[0];
  const float* Wq = (const float*)d_in[1];
  const float* bq = (const float*)d_in[2];
  const float* Wk = (const float*)d_in[3];
  const float* bk = (const float*)d_in[4];
  const float* Wv = (const float*)d_in[5];
  const float* bv = (const float*)d_in[6];
  const float* Wo = (const float*)d_in[7];
  const float* bo = (const float*)d_in[8];
  float* out = (float*)d_out;

  const size_t szX = (size_t)M * E;       // 4M elems
  const size_t szW = (size_t)E * E;       // 1M elems
  short* Xb  = (short*)d_ws;
  short* Wqb = Xb + szX;
  short* Wkb = Wqb + szW;
  short* Wvb = Wkb + szW;
  short* Wob = Wvb + szW;
  short* Qw  = Wob + szW;                 // later reused as Oh
  short* Kw  = Qw + szX;
  short* VTw = Kw + szX;                  // [1024][4096]; total ws 40 MB

  convert_kernel<<<4096, 256, 0, stream>>>(X, Wq, Wk, Wv, Wo, Xb);

  // Fused projections (C^T-store, 128x128, BK=32, XCD-chunked,
  // weight-axis-inner): z0 Q (A=Wq, scaled log2e/8), z1 K (A=Wk),
  // z2 V^T (A=X, B=Wv).
  const float kLog2eOver8 = 0.18033688011112042f;
  proj_kernel<<<768, 256, 0, stream>>>(
      Wqb, Wkb, Xb,
      Xb, Xb, Wvb,
      bq, bk, bv,
      (void*)Qw, (void*)Kw, (void*)VTw,
      kLog2eOver8, 1.0f, 1.0f, E, E, M);

  // 256 blocks x 512 threads (8 waves, q-tile 256): 1 block/CU, one
  // shared K/V staging copy per CU, reg-staged 2-deep prefetch (R9 form).
  flash_kernel<<<256, 512, 0, stream>>>(Qw, Kw, VTw, Qw /*Oh in-place*/);

  // Final: out[token][feat] = Oh@Wo^T + bo; A=Wo (m=feat), B=Oh (n=token),
  // 128x128 tile, 256 blocks (R12 form), f32x4 full-line stores.
  out_kernel<<<256, 256, 0, stream>>>(
      Wob, Wob, Wob,
      Qw, Qw, Qw,
      bo, bo, bo,
      (void*)out, (void*)out, (void*)out,
      1.0f, 1.0f, 1.0f, E, E, E);
}